// Round 5
// baseline (76.454 us; speedup 1.0000x reference)
//
#include <hip/hip_runtime.h>
#include <math.h>

#define IMG 256
#define TS 32
#define EBASE 736        // uint slot offset of packed E in ws
#define PHI_BASE 1088    // float-slot offset where phi planes start (byte 4352, 16B aligned)
#define NPIX (32 * 256 * 256)
#define PLANE NPIX       // halfs per plane

typedef _Float16 half_t;
typedef _Float16 half2_t __attribute__((ext_vector_type(2)));

__device__ __forceinline__ half2_t bc_h2(unsigned int u) {
    union { unsigned int u; half2_t h; } c; c.u = u; return c.h;
}
__device__ __forceinline__ unsigned int bc_u(half2_t h) {
    union { unsigned int u; half2_t h; } c; c.h = h; return c.u;
}

__device__ __forceinline__ float dot2(half2_t a, half2_t b, float c) {
#if __has_builtin(__builtin_amdgcn_fdot2)
    return __builtin_amdgcn_fdot2(a, b, c, false);
#else
    return fmaf((float)a.x, (float)b.x, fmaf((float)a.y, (float)b.y, c));
#endif
}

// ws layout (32-bit slots):
//   [0..728]           F fp32  (F[u][p][j], border corrections read this)
//   [EBASE..EBASE+287] E packed per j: 32 uints = 16 "even" + 16 "odd"
//   [PHI_BASE ...]     phi planes, 9 x NPIX halfs (split path only)
__global__ __launch_bounds__(1024) void kkan_precompute(
    const float* __restrict__ bw, const float* __restrict__ sw,
    const float* __restrict__ sc, const float* __restrict__ rw,
    float* __restrict__ ws)
{
    __shared__ float sF[729];
    const int tid = threadIdx.x;
    unsigned int* wse = (unsigned int*)ws + EBASE;
    if (tid < 729) {
        const int u = tid / 81, p = (tid / 9) % 9, j = tid % 9;
        float f = 0.f;
        for (int c = 0; c < 16; ++c) {
            const float w = (j < 8) ? sw[(c * 9 + p) * 8 + j] * sc[c * 9 + p]
                                    : bw[c * 9 + p];
            f += rw[c * 9 + u] * w;
        }
        sF[tid] = f;
        ws[tid] = f;
    } else if (tid < 729 + 288) {
        wse[tid - 729] = 0u;
    }
    __syncthreads();
    if (tid < 45) {
        const int j = tid / 5, sy = tid % 5;
        float e[5];
        for (int sx = 0; sx < 5; ++sx) {
            float acc = 0.f;
            for (int uy = 0; uy < 3; ++uy) {
                const int py = sy - uy;
                if (py < 0 || py > 2) continue;
                for (int ux = 0; ux < 3; ++ux) {
                    const int px = sx - ux;
                    if (px < 0 || px > 2) continue;
                    acc += sF[((uy * 3 + ux) * 9 + (py * 3 + px)) * 9 + j];
                }
            }
            e[sx] = acc;
        }
        unsigned int* oe = wse + j * 32 + sy * 3;
        oe[0] = bc_u(half2_t{(half_t)e[0], (half_t)e[1]});
        oe[1] = bc_u(half2_t{(half_t)e[2], (half_t)e[3]});
        oe[2] = bc_u(half2_t{(half_t)e[4], (half_t)0.f});
        unsigned int* oo = wse + j * 32 + 16 + sy * 3;
        oo[0] = bc_u(half2_t{(half_t)0.f, (half_t)e[0]});
        oo[1] = bc_u(half2_t{(half_t)e[1], (half_t)e[2]});
        oo[2] = bc_u(half2_t{(half_t)e[3], (half_t)e[4]});
    }
}

// ---------------------------------------------------------------------------
// K1: phi planes (8 spline bases + silu) for every pixel, SoA fp16 planes.
// Truncated-power form: phi_j = (c_j -4c_{j+1} +6c_{j+2} -4c_{j+3} +c_{j+4})/6,
// c_m = max(u0-m,0)^3, u0 = (v+2.2)*2.5. Branchless, exact 0 outside support.
// ---------------------------------------------------------------------------
__global__ __launch_bounds__(256) void kkan_phi(
    const float* __restrict__ x, half_t* __restrict__ phi)
{
    const int t = blockIdx.x * 256 + threadIdx.x;   // 8 px per thread
    const float4 xa = ((const float4*)x)[2 * t];
    const float4 xb = ((const float4*)x)[2 * t + 1];
    const float v[8] = {xa.x, xa.y, xa.z, xa.w, xb.x, xb.y, xb.z, xb.w};
    unsigned int ow[9][4];
    #pragma unroll
    for (int k = 0; k < 4; ++k) {
        float ph[2][9];
        #pragma unroll
        for (int e = 0; e < 2; ++e) {
            const float vv = v[2 * k + e];
            const float u0 = (vv + 2.2f) * 2.5f;
            float c[12];
            #pragma unroll
            for (int m = 0; m < 12; ++m) {
                const float tt = fmaxf(u0 - (float)m, 0.f);
                c[m] = tt * tt * tt;
            }
            #pragma unroll
            for (int j = 0; j < 8; ++j)
                ph[e][j] = (c[j] - 4.f * c[j + 1] + 6.f * c[j + 2]
                            - 4.f * c[j + 3] + c[j + 4]) * (1.f / 6.f);
            ph[e][8] = vv / (1.f + __expf(-vv));
        }
        #pragma unroll
        for (int j = 0; j < 9; ++j)
            ow[j][k] = bc_u(half2_t{(half_t)ph[0][j], (half_t)ph[1][j]});
    }
    #pragma unroll
    for (int j = 0; j < 9; ++j) {
        uint4 q; q.x = ow[j][0]; q.y = ow[j][1]; q.z = ow[j][2]; q.w = ow[j][3];
        ((uint4*)(phi + (size_t)j * PLANE))[t] = q;
    }
}

// ---------------------------------------------------------------------------
// K2: stage 36x36 phi halo per 32x32 tile into LDS, then 5x5x9 dot2 conv.
// ---------------------------------------------------------------------------
__global__ __launch_bounds__(256, 6) void kkan_conv(
    const half_t* __restrict__ phi, const float* __restrict__ ws,
    const float* __restrict__ rb, float* __restrict__ out)
{
    __shared__ __align__(16) half_t s_phi[9][36][40];   // 25.9 KB

    const int tid = threadIdx.x;
    const int gx0 = blockIdx.x * TS, gy0 = blockIdx.y * TS, b = blockIdx.z;
    const int bo = b * (IMG * IMG);
    unsigned int* sphw = (unsigned int*)s_phi;

    // ---- stage: 9 planes x 36 rows x 18 u32 (36 halfs from gx0-2) ----
    const bool interior = (blockIdx.x >= 1 && blockIdx.x <= 6 &&
                           blockIdx.y >= 1 && blockIdx.y <= 6);
    if (interior) {
        for (int idx = tid; idx < 5832; idx += 256) {
            const int i = idx / 18, c = idx % 18;
            const int j = i / 36, r = i % 36;
            const int gy = gy0 - 2 + r, gx = gx0 - 2 + 2 * c;
            const unsigned int w =
                *(const unsigned int*)&phi[(size_t)j * PLANE + bo + gy * IMG + gx];
            sphw[j * 720 + r * 20 + c] = w;
        }
    } else {
        for (int idx = tid; idx < 5832; idx += 256) {
            const int i = idx / 18, c = idx % 18;
            const int j = i / 36, r = i % 36;
            const int gy = gy0 - 2 + r, gx = gx0 - 2 + 2 * c;
            const bool rin = (unsigned)gy < (unsigned)IMG;
            unsigned int w;
            if (rin && gx >= 0 && gx + 1 < IMG) {
                w = *(const unsigned int*)&phi[(size_t)j * PLANE + bo + gy * IMG + gx];
            } else {
                // phi of padded x (v=0): planes 2,5 -> 1/48, planes 3,4 -> 23/48, else 0
                float p0f = 0.f;
                if (j == 2 || j == 5) p0f = 1.f / 48.f;
                else if (j == 3 || j == 4) p0f = 23.f / 48.f;
                const half_t p0h = (half_t)p0f;
                const half_t h0 = (rin && (unsigned)gx < (unsigned)IMG)
                    ? phi[(size_t)j * PLANE + bo + gy * IMG + gx] : p0h;
                const half_t h1 = (rin && (unsigned)(gx + 1) < (unsigned)IMG)
                    ? phi[(size_t)j * PLANE + bo + gy * IMG + gx + 1] : p0h;
                w = bc_u(half2_t{h0, h1});
            }
            sphw[j * 720 + r * 20 + c] = w;
        }
    }
    __syncthreads();

    // ---- 5x5x9 conv: 4 consecutive x pixels per thread, E from global ----
    const int ly = tid >> 3;
    const int lx0 = (tid & 7) * 4;

    const uint4* Eg = (const uint4*)((const unsigned int*)ws + EBASE);

    float aA0 = 0.f, aB0 = 0.f, aC0 = 0.f;
    float aA1 = 0.f, aB1 = 0.f, aC1 = 0.f;
    float aA2 = 0.f, aB2 = 0.f, aC2 = 0.f;
    float aA3 = 0.f, aB3 = 0.f, aC3 = 0.f;

    #pragma unroll
    for (int j = 0; j < 9; ++j) {
        unsigned int ej[32];
        #pragma unroll
        for (int q = 0; q < 8; ++q) {
            const uint4 t4 = Eg[j * 8 + q];
            ej[q * 4 + 0] = t4.x; ej[q * 4 + 1] = t4.y;
            ej[q * 4 + 2] = t4.z; ej[q * 4 + 3] = t4.w;
        }
        #pragma unroll
        for (int sy = 0; sy < 5; ++sy) {
            const half2_t ev0 = bc_h2(ej[sy * 3 + 0]);
            const half2_t ev1 = bc_h2(ej[sy * 3 + 1]);
            const half2_t ev2 = bc_h2(ej[sy * 3 + 2]);
            const half2_t od0 = bc_h2(ej[16 + sy * 3 + 0]);
            const half2_t od1 = bc_h2(ej[16 + sy * 3 + 1]);
            const half2_t od2 = bc_h2(ej[16 + sy * 3 + 2]);
            const uint2* pp = (const uint2*)&s_phi[j][ly + sy][lx0];
            const uint2 ph0 = pp[0], ph1 = pp[1];
            const half2_t P0 = bc_h2(ph0.x), P1 = bc_h2(ph0.y);
            const half2_t P2 = bc_h2(ph1.x), P3 = bc_h2(ph1.y);
            aA0 = dot2(P0, ev0, aA0); aB0 = dot2(P1, ev1, aB0); aC0 = dot2(P2, ev2, aC0);
            aA1 = dot2(P0, od0, aA1); aB1 = dot2(P1, od1, aB1); aC1 = dot2(P2, od2, aC1);
            aA2 = dot2(P1, ev0, aA2); aB2 = dot2(P2, ev1, aB2); aC2 = dot2(P3, ev2, aC2);
            aA3 = dot2(P1, od0, aA3); aB3 = dot2(P2, od1, aB3); aC3 = dot2(P3, od2, aC3);
        }
    }

    float a0 = aA0 + aB0 + aC0;
    float a1 = aA1 + aB1 + aC1;
    float a2 = aA2 + aB2 + aC2;
    float a3 = aA3 + aB3 + aC3;

    // ---- border correction (edge tiles only): F read straight from ws ----
    const int gy  = gy0 + ly;
    const int gxb = gx0 + lx0;
    if (gy < 2 || gy > 253 || gxb < 2 || gxb > 250) {
        #pragma unroll
        for (int i = 0; i < 4; ++i) {
            const int gx = gxb + i;
            float corr = 0.f;
            for (int uy = 0; uy < 3; ++uy) {
                const int qy = gy + uy - 1;
                for (int ux = 0; ux < 3; ++ux) {
                    const int qx = gx + ux - 1;
                    if ((unsigned)qy < (unsigned)IMG && (unsigned)qx < (unsigned)IMG)
                        continue;
                    for (int p = 0; p < 9; ++p) {
                        const int ry = ly + uy + (p / 3);
                        const int rx = lx0 + i + ux + (p % 3);
                        const float* fp = &ws[((uy * 3 + ux) * 9 + p) * 9];
                        for (int jj = 0; jj < 9; ++jj)
                            corr += fp[jj] * (float)s_phi[jj][ry][rx];
                    }
                }
            }
            if (i == 0) a0 -= corr;
            else if (i == 1) a1 -= corr;
            else if (i == 2) a2 -= corr;
            else a3 -= corr;
        }
    }

    const float rbv = rb[0];
    float4 o4; o4.x = a0 + rbv; o4.y = a1 + rbv; o4.z = a2 + rbv; o4.w = a3 + rbv;
    *(float4*)&out[(size_t)b * (IMG * IMG) + gy * IMG + gxb] = o4;
}

// ---------------------------------------------------------------------------
// Fallback fused kernel (round-4 version) if ws_size can't hold phi planes.
// ---------------------------------------------------------------------------
__global__ __launch_bounds__(256, 6) void kkan_fused_fb(
    const float* __restrict__ x, const float* __restrict__ ws,
    const float* __restrict__ rb, float* __restrict__ out)
{
    __shared__ __align__(16) half_t s_phi[9][36][40];

    const int tid = threadIdx.x;
    const int gx0 = blockIdx.x * TS, gy0 = blockIdx.y * TS, b = blockIdx.z;

    {
        uint4 z; z.x = 0u; z.y = 0u; z.z = 0u; z.w = 0u;
        uint4* p = (uint4*)s_phi;
        for (int i = tid; i < 1620; i += 256) p[i] = z;
    }
    __syncthreads();

    const float* xb = x + (size_t)b * (IMG * IMG);

    for (int pix = tid; pix < 36 * 36; pix += 256) {
        const int yy = pix / 36, xx = pix % 36;
        const int gy = gy0 - 2 + yy, gx = gx0 - 2 + xx;
        float v = 0.f;
        if ((unsigned)gy < (unsigned)IMG && (unsigned)gx < (unsigned)IMG)
            v = xb[gy * IMG + gx];

        const float sil = v / (1.f + __expf(-v));

        const int cell = (int)floorf((v + 2.2f) * 2.5f);
        if (cell >= 0 && cell <= 10) {
            const float g0 = (float)(cell - 3) * 0.4f - 1.0f;
            const float u = (v - g0) * 2.5f;
            const float um = 1.f - u, u2 = u * u, u3 = u2 * u;
            const float w0 = um * um * um * (1.f / 6.f);
            const float w1 = (3.f * u3 - 6.f * u2 + 4.f) * (1.f / 6.f);
            const float w2 = (-3.f * u3 + 3.f * u2 + 3.f * u + 1.f) * (1.f / 6.f);
            const float w3 = u3 * (1.f / 6.f);
            const int j0 = cell - 3;
            if (j0 >= 0 && j0 < 8)         s_phi[j0][yy][xx]     = (half_t)w0;
            if (j0 + 1 >= 0 && j0 + 1 < 8) s_phi[j0 + 1][yy][xx] = (half_t)w1;
            if (j0 + 2 >= 0 && j0 + 2 < 8) s_phi[j0 + 2][yy][xx] = (half_t)w2;
            if (j0 + 3 >= 0 && j0 + 3 < 8) s_phi[j0 + 3][yy][xx] = (half_t)w3;
        }
        s_phi[8][yy][xx] = (half_t)sil;
    }
    __syncthreads();

    const int ly = tid >> 3;
    const int lx0 = (tid & 7) * 4;
    const uint4* Eg = (const uint4*)((const unsigned int*)ws + EBASE);

    float aA0 = 0.f, aB0 = 0.f, aC0 = 0.f;
    float aA1 = 0.f, aB1 = 0.f, aC1 = 0.f;
    float aA2 = 0.f, aB2 = 0.f, aC2 = 0.f;
    float aA3 = 0.f, aB3 = 0.f, aC3 = 0.f;

    #pragma unroll
    for (int j = 0; j < 9; ++j) {
        unsigned int ej[32];
        #pragma unroll
        for (int q = 0; q < 8; ++q) {
            const uint4 t4 = Eg[j * 8 + q];
            ej[q * 4 + 0] = t4.x; ej[q * 4 + 1] = t4.y;
            ej[q * 4 + 2] = t4.z; ej[q * 4 + 3] = t4.w;
        }
        #pragma unroll
        for (int sy = 0; sy < 5; ++sy) {
            const half2_t ev0 = bc_h2(ej[sy * 3 + 0]);
            const half2_t ev1 = bc_h2(ej[sy * 3 + 1]);
            const half2_t ev2 = bc_h2(ej[sy * 3 + 2]);
            const half2_t od0 = bc_h2(ej[16 + sy * 3 + 0]);
            const half2_t od1 = bc_h2(ej[16 + sy * 3 + 1]);
            const half2_t od2 = bc_h2(ej[16 + sy * 3 + 2]);
            const uint2* pp = (const uint2*)&s_phi[j][ly + sy][lx0];
            const uint2 ph0 = pp[0], ph1 = pp[1];
            const half2_t P0 = bc_h2(ph0.x), P1 = bc_h2(ph0.y);
            const half2_t P2 = bc_h2(ph1.x), P3 = bc_h2(ph1.y);
            aA0 = dot2(P0, ev0, aA0); aB0 = dot2(P1, ev1, aB0); aC0 = dot2(P2, ev2, aC0);
            aA1 = dot2(P0, od0, aA1); aB1 = dot2(P1, od1, aB1); aC1 = dot2(P2, od2, aC1);
            aA2 = dot2(P1, ev0, aA2); aB2 = dot2(P2, ev1, aB2); aC2 = dot2(P3, ev2, aC2);
            aA3 = dot2(P1, od0, aA3); aB3 = dot2(P2, od1, aB3); aC3 = dot2(P3, od2, aC3);
        }
    }

    float a0 = aA0 + aB0 + aC0;
    float a1 = aA1 + aB1 + aC1;
    float a2 = aA2 + aB2 + aC2;
    float a3 = aA3 + aB3 + aC3;

    const int gy  = gy0 + ly;
    const int gxb = gx0 + lx0;
    if (gy < 2 || gy > 253 || gxb < 2 || gxb > 250) {
        #pragma unroll
        for (int i = 0; i < 4; ++i) {
            const int gx = gxb + i;
            float corr = 0.f;
            for (int uy = 0; uy < 3; ++uy) {
                const int qy = gy + uy - 1;
                for (int ux = 0; ux < 3; ++ux) {
                    const int qx = gx + ux - 1;
                    if ((unsigned)qy < (unsigned)IMG && (unsigned)qx < (unsigned)IMG)
                        continue;
                    for (int p = 0; p < 9; ++p) {
                        const int ry = ly + uy + (p / 3);
                        const int rx = lx0 + i + ux + (p % 3);
                        const float* fp = &ws[((uy * 3 + ux) * 9 + p) * 9];
                        for (int jj = 0; jj < 9; ++jj)
                            corr += fp[jj] * (float)s_phi[jj][ry][rx];
                    }
                }
            }
            if (i == 0) a0 -= corr;
            else if (i == 1) a1 -= corr;
            else if (i == 2) a2 -= corr;
            else a3 -= corr;
        }
    }

    const float rbv = rb[0];
    float4 o4; o4.x = a0 + rbv; o4.y = a1 + rbv; o4.z = a2 + rbv; o4.w = a3 + rbv;
    *(float4*)&out[(size_t)b * (IMG * IMG) + gy * IMG + gxb] = o4;
}

extern "C" void kernel_launch(void* const* d_in, const int* in_sizes, int n_in,
                              void* d_out, int out_size, void* d_ws, size_t ws_size,
                              hipStream_t stream) {
    const float* x             = (const float*)d_in[0];
    const float* base_w        = (const float*)d_in[1];
    const float* spline_w      = (const float*)d_in[2];
    const float* spline_scaler = (const float*)d_in[3];
    const float* restore_w     = (const float*)d_in[4];
    const float* restore_b     = (const float*)d_in[5];
    float* out = (float*)d_out;
    float* ws  = (float*)d_ws;

    kkan_precompute<<<dim3(1), dim3(1024), 0, stream>>>(
        base_w, spline_w, spline_scaler, restore_w, ws);

    const size_t need = (size_t)PHI_BASE * 4 + (size_t)9 * PLANE * 2;
    if (ws_size >= need) {
        half_t* phi = (half_t*)((char*)d_ws + (size_t)PHI_BASE * 4);
        kkan_phi<<<dim3(NPIX / 2048), dim3(256), 0, stream>>>(x, phi);
        kkan_conv<<<dim3(8, 8, 32), dim3(256), 0, stream>>>(phi, ws, restore_b, out);
    } else {
        kkan_fused_fb<<<dim3(8, 8, 32), dim3(256), 0, stream>>>(x, ws, restore_b, out);
    }
}

// Round 6
// 46.002 us; speedup vs baseline: 1.6620x; 1.6620x over previous
//
#include <hip/hip_runtime.h>
#include <math.h>

#define IMG 256
#define TS 32
#define EBASE 736   // uint-slot offset of packed E-pairs in ws

typedef _Float16 half_t;
typedef _Float16 half2_t __attribute__((ext_vector_type(2)));

__device__ __forceinline__ half2_t bc_h2(unsigned int u) {
    union { unsigned int u; half2_t h; } c; c.u = u; return c.h;
}
__device__ __forceinline__ unsigned int bc_u(half2_t h) {
    union { unsigned int u; half2_t h; } c; c.h = h; return c.u;
}

__device__ __forceinline__ float dot2(half2_t a, half2_t b, float c) {
#if __has_builtin(__builtin_amdgcn_fdot2)
    return __builtin_amdgcn_fdot2(a, b, c, false);
#else
    return fmaf((float)a.x, (float)b.x, fmaf((float)a.y, (float)b.y, c));
#endif
}

// ws layout (32-bit slots):
//   [0..728]            F fp32 (F[u][p][j], border corrections)
//   [EBASE..EBASE+199]  Ep pairs: uint half2(E[2jp],E[2jp+1]) at [jp][sy][8]
__global__ __launch_bounds__(1024) void kkan_precompute(
    const float* __restrict__ bw, const float* __restrict__ sw,
    const float* __restrict__ sc, const float* __restrict__ rw,
    float* __restrict__ ws)
{
    __shared__ float sF[729];
    const int tid = threadIdx.x;
    if (tid < 729) {
        const int u = tid / 81, p = (tid / 9) % 9, j = tid % 9;
        float f = 0.f;
        for (int c = 0; c < 16; ++c) {
            const float w = (j < 8) ? sw[(c * 9 + p) * 8 + j] * sc[c * 9 + p]
                                    : bw[c * 9 + p];
            f += rw[c * 9 + u] * w;
        }
        sF[tid] = f;
        ws[tid] = f;
    }
    __syncthreads();
    unsigned int* wse = (unsigned int*)ws + EBASE;
    if (tid < 200) {
        const int jp = tid / 40, rem = tid % 40, sy = rem / 8, sx = rem % 8;
        unsigned int val = 0u;
        if (sx < 5) {
            float e0 = 0.f, e1 = 0.f;
            for (int uy = 0; uy < 3; ++uy) {
                const int py = sy - uy; if (py < 0 || py > 2) continue;
                for (int ux = 0; ux < 3; ++ux) {
                    const int px = sx - ux; if (px < 0 || px > 2) continue;
                    const float* fb = &sF[((uy * 3 + ux) * 9 + (py * 3 + px)) * 9];
                    e0 += fb[2 * jp];
                    if (2 * jp + 1 < 9) e1 += fb[2 * jp + 1];
                }
            }
            val = bc_u(half2_t{(half_t)e0, (half_t)e1});
        }
        wse[tid] = val;
    }
}

// phi for one halo pixel -> 5 pair-plane dword stores (dense, branchless)
__device__ __forceinline__ void phi_store(unsigned int* s_phi, int pix, float v) {
    const int yy = pix / 36, xx = pix - yy * 36;
    const float sil = v / (1.f + __expf(-v));
    float u0 = (v + 2.2f) * 2.5f;
    u0 = fminf(fmaxf(u0, 0.f), 11.f);   // exact 0 outside support, kills cancellation
    float c[12];
    #pragma unroll
    for (int m = 0; m < 12; ++m) {
        const float d = fmaxf(u0 - (float)m, 0.f);
        c[m] = d * d * d;
    }
    float ph[8];
    #pragma unroll
    for (int j = 0; j < 8; ++j)
        ph[j] = (c[j] - 4.f * c[j + 1] + 6.f * c[j + 2]
                 - 4.f * c[j + 3] + c[j + 4]) * (1.f / 6.f);
    unsigned int* dst = &s_phi[yy * 36 + xx];
    dst[0 * 1296] = bc_u(half2_t{(half_t)ph[0], (half_t)ph[1]});
    dst[1 * 1296] = bc_u(half2_t{(half_t)ph[2], (half_t)ph[3]});
    dst[2 * 1296] = bc_u(half2_t{(half_t)ph[4], (half_t)ph[5]});
    dst[3 * 1296] = bc_u(half2_t{(half_t)ph[6], (half_t)ph[7]});
    dst[4 * 1296] = bc_u(half2_t{(half_t)sil,   (half_t)0.f});
}

__device__ __forceinline__ float phi_at(const unsigned int* s_phi, int j, int r, int c) {
    const half2_t h = bc_h2(s_phi[(j >> 1) * 1296 + r * 36 + c]);
    return (j & 1) ? (float)h.y : (float)h.x;
}

__global__ __launch_bounds__(256, 6) void kkan_fused(
    const float* __restrict__ x, const float* __restrict__ ws,
    const float* __restrict__ rb, float* __restrict__ out)
{
    __shared__ __align__(16) unsigned int s_phi[5 * 36 * 36];   // 25.9 KB

    const int tid = threadIdx.x;
    const int gx0 = blockIdx.x * TS, gy0 = blockIdx.y * TS, b = blockIdx.z;
    const float* xb = x + (size_t)b * (IMG * IMG);

    // ---- hoisted halo loads (latency overlaps phi arithmetic) ----
    float vx[6];
    #pragma unroll
    for (int it = 0; it < 6; ++it) {
        const int pix = tid + it * 256;
        float v = 0.f;
        if (it < 5 || tid < 16) {
            const int yy = pix / 36, xx = pix - yy * 36;
            const int gy = gy0 - 2 + yy, gx = gx0 - 2 + xx;
            if ((unsigned)gy < (unsigned)IMG && (unsigned)gx < (unsigned)IMG)
                v = xb[gy * IMG + gx];
        }
        vx[it] = v;
    }

    // ---- phi: dense pair-plane writes, no zero-fill needed ----
    #pragma unroll
    for (int it = 0; it < 5; ++it) phi_store(s_phi, tid + it * 256, vx[it]);
    if (tid < 16) phi_store(s_phi, tid + 1280, vx[5]);
    __syncthreads();

    // ---- 5x5 conv over 5 pair-planes: 4 px/thread, b128 phi reads ----
    const int ly = tid >> 3;
    const int lx0 = (tid & 7) * 4;
    const unsigned int* Eu = (const unsigned int*)ws + EBASE;

    float aA0 = 0.f, aB0 = 0.f, aA1 = 0.f, aB1 = 0.f;
    float aA2 = 0.f, aB2 = 0.f, aA3 = 0.f, aB3 = 0.f;

    #pragma unroll
    for (int jp = 0; jp < 5; ++jp) {
        #pragma unroll
        for (int sy = 0; sy < 5; ++sy) {
            const unsigned int* eb = &Eu[(jp * 5 + sy) * 8];
            const half2_t e0 = bc_h2(eb[0]);
            const half2_t e1 = bc_h2(eb[1]);
            const half2_t e2 = bc_h2(eb[2]);
            const half2_t e3 = bc_h2(eb[3]);
            const half2_t e4 = bc_h2(eb[4]);
            const unsigned int* prow = &s_phi[(jp * 36 + ly + sy) * 36 + lx0];
            const uint4 pa = *(const uint4*)prow;
            const uint4 pb = *(const uint4*)(prow + 4);
            const half2_t q0 = bc_h2(pa.x), q1 = bc_h2(pa.y);
            const half2_t q2 = bc_h2(pa.z), q3 = bc_h2(pa.w);
            const half2_t q4 = bc_h2(pb.x), q5 = bc_h2(pb.y);
            const half2_t q6 = bc_h2(pb.z), q7 = bc_h2(pb.w);
            aA0 = dot2(q0, e0, dot2(q2, e2, dot2(q4, e4, aA0)));
            aB0 = dot2(q1, e1, dot2(q3, e3, aB0));
            aA1 = dot2(q1, e0, dot2(q3, e2, dot2(q5, e4, aA1)));
            aB1 = dot2(q2, e1, dot2(q4, e3, aB1));
            aA2 = dot2(q2, e0, dot2(q4, e2, dot2(q6, e4, aA2)));
            aB2 = dot2(q3, e1, dot2(q5, e3, aB2));
            aA3 = dot2(q3, e0, dot2(q5, e2, dot2(q7, e4, aA3)));
            aB3 = dot2(q4, e1, dot2(q6, e3, aB3));
        }
    }
    float a0 = aA0 + aB0, a1 = aA1 + aB1, a2 = aA2 + aB2, a3 = aA3 + aB3;

    // ---- border correction (edge pixels only): F from ws (L2) ----
    const int gy  = gy0 + ly;
    const int gxb = gx0 + lx0;
    if (gy < 2 || gy > 253 || gxb < 2 || gxb > 250) {
        #pragma unroll
        for (int i = 0; i < 4; ++i) {
            const int gx = gxb + i;
            float corr = 0.f;
            for (int uy = 0; uy < 3; ++uy) {
                const int qy = gy + uy - 1;
                for (int ux = 0; ux < 3; ++ux) {
                    const int qx = gx + ux - 1;
                    if ((unsigned)qy < (unsigned)IMG && (unsigned)qx < (unsigned)IMG)
                        continue;
                    for (int p = 0; p < 9; ++p) {
                        const int ry = ly + uy + (p / 3);
                        const int rx = lx0 + i + ux + (p % 3);
                        const float* fp = &ws[((uy * 3 + ux) * 9 + p) * 9];
                        for (int jj = 0; jj < 9; ++jj)
                            corr += fp[jj] * phi_at(s_phi, jj, ry, rx);
                    }
                }
            }
            if (i == 0) a0 -= corr;
            else if (i == 1) a1 -= corr;
            else if (i == 2) a2 -= corr;
            else a3 -= corr;
        }
    }

    const float rbv = rb[0];
    float4 o4; o4.x = a0 + rbv; o4.y = a1 + rbv; o4.z = a2 + rbv; o4.w = a3 + rbv;
    *(float4*)&out[(size_t)b * (IMG * IMG) + gy * IMG + gxb] = o4;
}

extern "C" void kernel_launch(void* const* d_in, const int* in_sizes, int n_in,
                              void* d_out, int out_size, void* d_ws, size_t ws_size,
                              hipStream_t stream) {
    const float* x             = (const float*)d_in[0];
    const float* base_w        = (const float*)d_in[1];
    const float* spline_w      = (const float*)d_in[2];
    const float* spline_scaler = (const float*)d_in[3];
    const float* restore_w     = (const float*)d_in[4];
    const float* restore_b     = (const float*)d_in[5];
    float* out = (float*)d_out;
    float* ws  = (float*)d_ws;

    kkan_precompute<<<dim3(1), dim3(1024), 0, stream>>>(
        base_w, spline_w, spline_scaler, restore_w, ws);

    kkan_fused<<<dim3(8, 8, 32), dim3(256), 0, stream>>>(x, ws, restore_b, out);
}